// Round 3
// baseline (1333.285 us; speedup 1.0000x reference)
//
#include <hip/hip_runtime.h>

#define DEV static __device__ __forceinline__

typedef __attribute__((ext_vector_type(8))) short v8s;
typedef __attribute__((ext_vector_type(4))) float v4f;

constexpr int Bn = 4, Sn = 1024, Dn = 768, NHn = 12, HDn = 64, En = 8, DFFn = 3072;
constexpr int Tn = Bn * Sn;          // 4096 tokens
constexpr int NROWS = 2 * Tn;        // 8192 gathered expert rows
constexpr int DHALF = DFFn / 2;      // 1536 (MoE processed in two DFF halves)
constexpr size_t MB = 1024 * 1024;

// ---- workspace map (~97.6 MB; lifetime-overlaid regions) ----
// [0,12)    vf (V out, f32)            -> x2f (attn residual out, lives to end)
// [12,36)   h1f (12, LN1 out) -> schunk (24, 6-head scores) -> eh (24, bf16 8192x1536)
// [36,48)   of (f32 PV accum, atomic)  -> buf (f32 MoE accum, atomic)
// [48,60)   qf (Q out f32)             -> h2f (LN2 out f32, lives through MoE)
// [60,78)   khi(6)+klo(6)+vthi(6)      -> whalf (18, per-half transposed expert weights)
// [78,84)   vtlo(6)                    -> (dead in MoE era)
// [84,93)   wqTh,wqTl,wkTh,wkTl,wvTh,wvTl,woTh,woTl (8 x 1.125)
// [93,93.2) gates/ind/meta/rows

DEV float bf2f(unsigned short h) {
    union { unsigned int u; float f; } c; c.u = ((unsigned int)h) << 16; return c.f;
}
DEV unsigned short f2bf(float f) {   // round-to-nearest-even
    union { float f; unsigned int u; } c; c.f = f;
    return (unsigned short)((c.u + 0x7fffu + ((c.u >> 16) & 1u)) >> 16);
}
DEV v4f mfma16(v8s a, v8s b, v4f c) {
    return __builtin_amdgcn_mfma_f32_16x16x32_bf16(a, b, c, 0, 0, 0);
}

// ---------------- transpose fp32 src -> bf16 hi (+ optional lo) ----------------
// logical src element (r,c) at src[r*src_ld + c]; dst (c,r) at dst[c*dst_ld + r]
// grid (Ctiles, Rtiles, Z); 64x64 tiles
__global__ __launch_bounds__(256) void transpose_f32(const float* __restrict__ src,
                                                     int src_ld, long src_zs,
                                                     unsigned short* __restrict__ dsthi,
                                                     unsigned short* __restrict__ dstlo,
                                                     int dst_ld, long dst_zs) {
    src += (long)blockIdx.z * src_zs;
    dsthi += (long)blockIdx.z * dst_zs;
    if (dstlo) dstlo += (long)blockIdx.z * dst_zs;
    __shared__ float tile[64][65];
    int tid = threadIdx.x, tx = blockIdx.x, ty = blockIdx.y;
    int r = tid >> 2, c0 = (tid & 3) * 16;
    const float* sp = src + (long)(ty * 64 + r) * src_ld + tx * 64 + c0;
#pragma unroll
    for (int i = 0; i < 4; ++i) {
        float4 f = *(const float4*)(sp + i * 4);
        tile[r][c0 + i * 4 + 0] = f.x;
        tile[r][c0 + i * 4 + 1] = f.y;
        tile[r][c0 + i * 4 + 2] = f.z;
        tile[r][c0 + i * 4 + 3] = f.w;
    }
    __syncthreads();
    int dl = tid >> 2, s0 = (tid & 3) * 16;
    unsigned short hh[16] __attribute__((aligned(16)));
    unsigned short ll[16] __attribute__((aligned(16)));
#pragma unroll
    for (int i = 0; i < 16; ++i) {
        float f = tile[s0 + i][dl];
        unsigned short h0 = f2bf(f);
        hh[i] = h0;
        ll[i] = f2bf(f - bf2f(h0));
    }
    long o = (long)(tx * 64 + dl) * dst_ld + ty * 64 + s0;
    *(uint4*)(dsthi + o) = ((uint4*)hh)[0];
    *(uint4*)(dsthi + o + 8) = ((uint4*)hh)[1];
    if (dstlo) {
        *(uint4*)(dstlo + o) = ((uint4*)ll)[0];
        *(uint4*)(dstlo + o + 8) = ((uint4*)ll)[1];
    }
}

// ---------------- LayerNorm (f32 in, f32 out) ----------------
__global__ __launch_bounds__(256) void ln_kernel(const float* __restrict__ in_f,
                                                 const float* __restrict__ sc,
                                                 const float* __restrict__ bi,
                                                 float* __restrict__ outf) {
    int row = blockIdx.x, tid = threadIdx.x;
    long base = (long)row * Dn;
    float x[3];
#pragma unroll
    for (int j = 0; j < 3; ++j) x[j] = in_f[base + tid + j * 256];
    __shared__ float red[4];
    float s = x[0] + x[1] + x[2];
    for (int off = 32; off; off >>= 1) s += __shfl_down(s, off, 64);
    if ((tid & 63) == 0) red[tid >> 6] = s;
    __syncthreads();
    float mean = (red[0] + red[1] + red[2] + red[3]) * (1.0f / Dn);
    __syncthreads();
    float ss = 0.f;
#pragma unroll
    for (int j = 0; j < 3; ++j) { float d0 = x[j] - mean; ss += d0 * d0; }
    for (int off = 32; off; off >>= 1) ss += __shfl_down(ss, off, 64);
    if ((tid & 63) == 0) red[tid >> 6] = ss;
    __syncthreads();
    float var = (red[0] + red[1] + red[2] + red[3]) * (1.0f / Dn);
    float rstd = 1.0f / sqrtf(var + 1e-5f);
#pragma unroll
    for (int j = 0; j < 3; ++j) {
        int d = tid + j * 256;
        outf[base + d] = (x[j] - mean) * rstd * sc[d] + bi[d];
    }
}

// ---------------- split-bf16 fp32-grade GEMM ----------------
// C = A(f32, split hi/lo in staging) @ B^T (+bias)(+resid)
// B given TRANSPOSED [N,K] bf16 (hi + optional lo). BM=128 BN=64 BK=32.
// z decomposition: zi = z/zdiv selects A/B/C slab; ks = z%zdiv selects K-slice.
// catomic: atomicAdd f32 into Cf instead of plain store.
__global__ __launch_bounds__(256) void gemm_split(const float* __restrict__ A, int lda, long za,
                                                  const unsigned short* __restrict__ Bhi,
                                                  const unsigned short* __restrict__ Blo, int ldb, long zb,
                                                  const float* __restrict__ bias,
                                                  const float* __restrict__ resid,
                                                  float* __restrict__ Cf,
                                                  unsigned short* __restrict__ Chi,
                                                  unsigned short* __restrict__ Clo,
                                                  int ldc, long zc, int K, int zdiv, int catomic) {
    int z = blockIdx.z;
    int zi = z / zdiv, ks = z - zi * zdiv;
    int Klen = K / zdiv, k0base = ks * Klen;
    A += (long)zi * za;
    Bhi += (long)zi * zb;
    if (Blo) Blo += (long)zi * zb;
    long coff = (long)zi * zc;
    int n0 = blockIdx.x * 64, m0 = blockIdx.y * 128;
    int tid = threadIdx.x, w = tid >> 6, lane = tid & 63, quad = lane >> 4, l16 = lane & 15;
    __shared__ unsigned short Ah[128][40], Al[128][40], Bh[64][40], Bl[64][40];
    v4f acc[2][4] = {};
    int ar = tid >> 1, ac = (tid & 1) * 16;
    int br = tid >> 2, bc = (tid & 3) * 8;
    const bool hasblo = (Blo != nullptr);
    int nsteps = Klen >> 5;
    for (int kt = 0; kt < nsteps; ++kt) {
        int k0 = k0base + (kt << 5);
        const float* ap = A + (long)(m0 + ar) * lda + (k0 + ac);
        float4 f0 = *(const float4*)(ap);
        float4 f1 = *(const float4*)(ap + 4);
        float4 f2 = *(const float4*)(ap + 8);
        float4 f3 = *(const float4*)(ap + 12);
        float fv[16] = {f0.x, f0.y, f0.z, f0.w, f1.x, f1.y, f1.z, f1.w,
                        f2.x, f2.y, f2.z, f2.w, f3.x, f3.y, f3.z, f3.w};
        unsigned short hh[16] __attribute__((aligned(16)));
        unsigned short ll[16] __attribute__((aligned(16)));
#pragma unroll
        for (int i = 0; i < 16; ++i) {
            unsigned short h = f2bf(fv[i]);
            hh[i] = h;
            ll[i] = f2bf(fv[i] - bf2f(h));
        }
        *(uint4*)&Ah[ar][ac] = ((uint4*)hh)[0];
        *(uint4*)&Ah[ar][ac + 8] = ((uint4*)hh)[1];
        *(uint4*)&Al[ar][ac] = ((uint4*)ll)[0];
        *(uint4*)&Al[ar][ac + 8] = ((uint4*)ll)[1];
        const unsigned short* bp = Bhi + (long)(n0 + br) * ldb + (k0 + bc);
        *(uint4*)&Bh[br][bc] = *(const uint4*)bp;
        if (hasblo)
            *(uint4*)&Bl[br][bc] = *(const uint4*)(Blo + (long)(n0 + br) * ldb + (k0 + bc));
        __syncthreads();
        v8s ah0 = *(const v8s*)&Ah[w * 32 + l16][quad * 8];
        v8s ah1 = *(const v8s*)&Ah[w * 32 + 16 + l16][quad * 8];
        v8s al0 = *(const v8s*)&Al[w * 32 + l16][quad * 8];
        v8s al1 = *(const v8s*)&Al[w * 32 + 16 + l16][quad * 8];
#pragma unroll
        for (int nt = 0; nt < 4; ++nt) {
            v8s bh = *(const v8s*)&Bh[nt * 16 + l16][quad * 8];
            acc[0][nt] = mfma16(ah0, bh, acc[0][nt]);
            acc[1][nt] = mfma16(ah1, bh, acc[1][nt]);
            acc[0][nt] = mfma16(al0, bh, acc[0][nt]);
            acc[1][nt] = mfma16(al1, bh, acc[1][nt]);
            if (hasblo) {
                v8s bl = *(const v8s*)&Bl[nt * 16 + l16][quad * 8];
                acc[0][nt] = mfma16(ah0, bl, acc[0][nt]);
                acc[1][nt] = mfma16(ah1, bl, acc[1][nt]);
                acc[0][nt] = mfma16(al0, bl, acc[0][nt]);
                acc[1][nt] = mfma16(al1, bl, acc[1][nt]);
            }
        }
        __syncthreads();
    }
#pragma unroll
    for (int mt = 0; mt < 2; ++mt)
#pragma unroll
        for (int nt = 0; nt < 4; ++nt)
#pragma unroll
            for (int r = 0; r < 4; ++r) {
                int row = m0 + w * 32 + mt * 16 + quad * 4 + r;
                int col = n0 + nt * 16 + l16;
                float v = acc[mt][nt][r];
                if (bias) v += bias[col];
                long ci = coff + (long)row * ldc + col;
                if (resid) v += resid[ci];
                if (catomic) {
                    atomicAdd(&Cf[ci], v);
                } else {
                    if (Cf) Cf[ci] = v;
                    if (Chi) {
                        unsigned short h = f2bf(v);
                        Chi[ci] = h;
                        if (Clo) Clo[ci] = f2bf(v - bf2f(h));
                    }
                }
            }
}

// ---------------- V transpose+split: v[b,s,h,d] f32 -> vt[g=b*12+h][d][s] bf16 hi/lo ----------
__global__ __launch_bounds__(256) void vtrans(const float* __restrict__ vf,
                                              unsigned short* __restrict__ vthi,
                                              unsigned short* __restrict__ vtlo) {
    int g = blockIdx.z, b = g / NHn, h = g % NHn;
    int stile = blockIdx.x, tid = threadIdx.x;
    __shared__ float tile[64][65];
    int sl = tid >> 2, c0 = (tid & 3) * 16;
    const float* vp = vf + (long)(b * Sn + stile * 64 + sl) * Dn + h * 64 + c0;
#pragma unroll
    for (int i = 0; i < 4; ++i) {
        float4 f = *(const float4*)(vp + i * 4);
        tile[sl][c0 + i * 4 + 0] = f.x;
        tile[sl][c0 + i * 4 + 1] = f.y;
        tile[sl][c0 + i * 4 + 2] = f.z;
        tile[sl][c0 + i * 4 + 3] = f.w;
    }
    __syncthreads();
    int dl = tid >> 2, s0 = (tid & 3) * 16;
    unsigned short hh[16] __attribute__((aligned(16)));
    unsigned short ll[16] __attribute__((aligned(16)));
#pragma unroll
    for (int i = 0; i < 16; ++i) {
        float f = tile[s0 + i][dl];
        unsigned short h0 = f2bf(f);
        hh[i] = h0;
        ll[i] = f2bf(f - bf2f(h0));
    }
    long o = (long)(g * 64 + dl) * Sn + stile * 64 + s0;
    *(uint4*)(vthi + o) = ((uint4*)hh)[0];
    *(uint4*)(vthi + o + 8) = ((uint4*)hh)[1];
    *(uint4*)(vtlo + o) = ((uint4*)ll)[0];
    *(uint4*)(vtlo + o + 8) = ((uint4*)ll)[1];
}

// ---------------- softmax over rows of 1024 (scale 1/8 applied) ----------------
__global__ __launch_bounds__(256) void softmax_rows(float* __restrict__ S) {
    long base = (long)blockIdx.x * 1024;
    int tid = threadIdx.x;
    float4 v = *(float4*)(S + base + tid * 4);
    v.x *= 0.125f; v.y *= 0.125f; v.z *= 0.125f; v.w *= 0.125f;
    __shared__ float redm[4], reds[4];
    float m = fmaxf(fmaxf(v.x, v.y), fmaxf(v.z, v.w));
    for (int off = 32; off; off >>= 1) m = fmaxf(m, __shfl_down(m, off, 64));
    if ((tid & 63) == 0) redm[tid >> 6] = m;
    __syncthreads();
    float M = fmaxf(fmaxf(redm[0], redm[1]), fmaxf(redm[2], redm[3]));
    float e0 = expf(v.x - M), e1 = expf(v.y - M), e2 = expf(v.z - M), e3 = expf(v.w - M);
    float s = e0 + e1 + e2 + e3;
    for (int off = 32; off; off >>= 1) s += __shfl_down(s, off, 64);
    if ((tid & 63) == 0) reds[tid >> 6] = s;
    __syncthreads();
    float inv = 1.0f / (reds[0] + reds[1] + reds[2] + reds[3]);
    float4 o = {e0 * inv, e1 * inv, e2 * inv, e3 * inv};
    *(float4*)(S + base + tid * 4) = o;
}

// ---------------- router: logits, noisy top-2, gates, counts (all f32) ----------------
__global__ __launch_bounds__(256) void router_kernel(const float* __restrict__ h2f,
                                                     const float* __restrict__ rw,
                                                     const float* __restrict__ rb,
                                                     const float* __restrict__ nw,
                                                     const float* __restrict__ nb,
                                                     const float* __restrict__ noise,
                                                     float* __restrict__ gates,
                                                     int* __restrict__ ind,
                                                     int* __restrict__ counts) {
    int t = blockIdx.x, tid = threadIdx.x, w = tid >> 6, lane = tid & 63;
    const float* W = (w < 2) ? rw : nw;
    int ebase = (w & 1) * 4;
    float acc[4] = {0.f, 0.f, 0.f, 0.f};
    const float* hp = h2f + (long)t * Dn;
    for (int d = lane; d < Dn; d += 64) {
        float hv = hp[d];
#pragma unroll
        for (int j = 0; j < 4; ++j) acc[j] += hv * W[d * En + ebase + j];
    }
    __shared__ float red[16];
#pragma unroll
    for (int j = 0; j < 4; ++j) {
        float a = acc[j];
        for (int off = 32; off; off >>= 1) a += __shfl_down(a, off, 64);
        if (lane == 0) red[w * 4 + j] = a;
    }
    __syncthreads();
    if (tid == 0) {
        float noisy[8];
#pragma unroll
        for (int e = 0; e < 8; ++e) {
            float lg = red[e] + rb[e];
            float nv = red[8 + e] + nb[e];
            float sp = fmaxf(nv, 0.f) + log1pf(expf(-fabsf(nv)));
            noisy[e] = lg + noise[(long)t * En + e] * sp;
        }
        int i0 = 0;
        for (int e = 1; e < 8; ++e) if (noisy[e] > noisy[i0]) i0 = e;
        int i1 = (i0 == 0) ? 1 : 0;
        for (int e = 0; e < 8; ++e) if (e != i0 && noisy[e] > noisy[i1]) i1 = e;
        float mm = fmaxf(noisy[i0], noisy[i1]);
        float e0 = expf(noisy[i0] - mm), e1 = expf(noisy[i1] - mm);
        float inv = 1.0f / (e0 + e1);
        gates[t] = e0 * inv;
        gates[Tn + t] = e1 * inv;
        ind[t] = i0;
        ind[Tn + t] = i1;
        atomicAdd(&counts[i0], 1);
        atomicAdd(&counts[i1], 1);
    }
}

__global__ void zero16(int* p) { if (threadIdx.x < 16) p[threadIdx.x] = 0; }

__global__ void prefix_kernel(const int* __restrict__ counts, int* __restrict__ basep) {
    basep[0] = 0;
    for (int e = 0; e < 8; ++e) basep[e + 1] = basep[e] + counts[e];
}

__global__ __launch_bounds__(256) void build_rows(const int* __restrict__ ind,
                                                  const int* __restrict__ basep,
                                                  int* __restrict__ cursor,
                                                  int* __restrict__ rows) {
    int t = blockIdx.x * 256 + threadIdx.x;
#pragma unroll
    for (int s0 = 0; s0 < 2; ++s0) {
        int e = ind[s0 * Tn + t];
        int pos = atomicAdd(&cursor[e], 1);
        rows[basep[e] + pos] = t * 2 + s0;
    }
}

// ---------------- MoE stage 1 (per DFF half): eh = relu(h2 @ W1t[e]^T + b1) ----------------
// h2 read as f32, converted to bf16 during staging. BM=BN=128, BK=32.
__global__ __launch_bounds__(256) void moe_gemm1(const float* __restrict__ h2f,
                                                 const unsigned short* __restrict__ W1t,
                                                 const float* __restrict__ eb1,
                                                 const int* __restrict__ rows,
                                                 const int* __restrict__ meta,
                                                 unsigned short* __restrict__ eh,
                                                 int half) {
    int e = blockIdx.z;
    int cnt = meta[e];
    int mb = blockIdx.y * 128;
    if (mb >= cnt) return;
    int base_e = meta[16 + e];
    int valid = cnt - mb; if (valid > 128) valid = 128;
    int tid = threadIdx.x;
    __shared__ int toks[128];
    if (tid < 128) {
        int idx = mb + tid;
        toks[tid] = rows[base_e + (idx < cnt ? idx : 0)];
    }
    __shared__ unsigned short As[128][40], Bs[128][40];
    int w = tid >> 6, lane = tid & 63, quad = lane >> 4, l16 = lane & 15;
    int wm = w >> 1, wn = w & 1;
    v4f acc[4][4] = {};
    int ar = tid >> 1, ac = (tid & 1) * 16;
    int nb0 = blockIdx.x * 128;
    const unsigned short* Wb = W1t + (long)e * DHALF * Dn;
    __syncthreads();
    for (int kt = 0; kt < Dn / 32; ++kt) {
        int k0 = kt * 32;
        int tok = toks[ar] >> 1;
        const float* apg = h2f + (long)tok * Dn + k0 + ac;
        float4 f0 = ((const float4*)apg)[0];
        float4 f1 = ((const float4*)apg)[1];
        float4 f2 = ((const float4*)apg)[2];
        float4 f3 = ((const float4*)apg)[3];
        float fv[16] = {f0.x, f0.y, f0.z, f0.w, f1.x, f1.y, f1.z, f1.w,
                        f2.x, f2.y, f2.z, f2.w, f3.x, f3.y, f3.z, f3.w};
        unsigned short hh[16] __attribute__((aligned(16)));
#pragma unroll
        for (int i = 0; i < 16; ++i) hh[i] = f2bf(fv[i]);
        *(uint4*)&As[ar][ac] = ((uint4*)hh)[0];
        *(uint4*)&As[ar][ac + 8] = ((uint4*)hh)[1];
        const unsigned short* bpg = Wb + (long)(nb0 + ar) * Dn + k0 + ac;
        *(uint4*)&Bs[ar][ac] = ((const uint4*)bpg)[0];
        *(uint4*)&Bs[ar][ac + 8] = ((const uint4*)bpg)[1];
        __syncthreads();
        v8s af[4];
#pragma unroll
        for (int mt = 0; mt < 4; ++mt) af[mt] = *(const v8s*)&As[wm * 64 + mt * 16 + l16][quad * 8];
#pragma unroll
        for (int nt = 0; nt < 4; ++nt) {
            v8s bb = *(const v8s*)&Bs[wn * 64 + nt * 16 + l16][quad * 8];
#pragma unroll
            for (int mt = 0; mt < 4; ++mt) acc[mt][nt] = mfma16(af[mt], bb, acc[mt][nt]);
        }
        __syncthreads();
    }
#pragma unroll
    for (int mt = 0; mt < 4; ++mt)
#pragma unroll
        for (int nt = 0; nt < 4; ++nt)
#pragma unroll
            for (int r = 0; r < 4; ++r) {
                int rl = wm * 64 + mt * 16 + quad * 4 + r;
                if (rl < valid) {
                    int col = nb0 + wn * 64 + nt * 16 + l16;
                    float v = acc[mt][nt][r] + eb1[e * DFFn + half * DHALF + col];
                    v = fmaxf(v, 0.f);
                    eh[(long)(base_e + mb + rl) * DHALF + col] = f2bf(v);
                }
            }
}

// ---------------- MoE stage 2 (per DFF half): buf[tok] += gate*(eh @ W2t[e]^T (+b2)) --------
__global__ __launch_bounds__(256) void moe_gemm2(const unsigned short* __restrict__ eh,
                                                 const unsigned short* __restrict__ W2t,
                                                 const float* __restrict__ eb2,
                                                 const int* __restrict__ rows,
                                                 const int* __restrict__ meta,
                                                 const float* __restrict__ gates,
                                                 float* __restrict__ buf) {
    int e = blockIdx.z;
    int cnt = meta[e];
    int mb = blockIdx.y * 128;
    if (mb >= cnt) return;
    int base_e = meta[16 + e];
    int valid = cnt - mb; if (valid > 128) valid = 128;
    int tid = threadIdx.x;
    __shared__ int toks[128];
    if (tid < 128) {
        int idx = mb + tid;
        toks[tid] = rows[base_e + (idx < cnt ? idx : 0)];
    }
    __shared__ unsigned short As[128][40], Bs[128][40];
    int w = tid >> 6, lane = tid & 63, quad = lane >> 4, l16 = lane & 15;
    int wm = w >> 1, wn = w & 1;
    v4f acc[4][4] = {};
    int ar = tid >> 1, ac = (tid & 1) * 16;
    int nb0 = blockIdx.x * 128;
    const unsigned short* Wb = W2t + (long)e * Dn * DHALF;
    __syncthreads();
    for (int kt = 0; kt < DHALF / 32; ++kt) {
        int k0 = kt * 32;
        long arow = (long)base_e + mb + ar;
        if (arow > NROWS - 1) arow = NROWS - 1;
        const unsigned short* apg = eh + arow * DHALF + k0 + ac;
        *(uint4*)&As[ar][ac] = ((const uint4*)apg)[0];
        *(uint4*)&As[ar][ac + 8] = ((const uint4*)apg)[1];
        const unsigned short* bpg = Wb + (long)(nb0 + ar) * DHALF + k0 + ac;
        *(uint4*)&Bs[ar][ac] = ((const uint4*)bpg)[0];
        *(uint4*)&Bs[ar][ac + 8] = ((const uint4*)bpg)[1];
        __syncthreads();
        v8s af[4];
#pragma unroll
        for (int mt = 0; mt < 4; ++mt) af[mt] = *(const v8s*)&As[wm * 64 + mt * 16 + l16][quad * 8];
#pragma unroll
        for (int nt = 0; nt < 4; ++nt) {
            v8s bb = *(const v8s*)&Bs[wn * 64 + nt * 16 + l16][quad * 8];
#pragma unroll
            for (int mt = 0; mt < 4; ++mt) acc[mt][nt] = mfma16(af[mt], bb, acc[mt][nt]);
        }
        __syncthreads();
    }
#pragma unroll
    for (int mt = 0; mt < 4; ++mt)
#pragma unroll
        for (int nt = 0; nt < 4; ++nt)
#pragma unroll
            for (int r = 0; r < 4; ++r) {
                int rl = wm * 64 + mt * 16 + quad * 4 + r;
                if (rl < valid) {
                    int col = nb0 + wn * 64 + nt * 16 + l16;
                    int code = toks[rl];
                    int tok = code >> 1, slot = code & 1;
                    float g = gates[slot * Tn + tok];
                    float v = acc[mt][nt][r];
                    if (eb2) v += eb2[e * Dn + col];
                    atomicAdd(&buf[(long)tok * Dn + col], v * g);
                }
            }
}

// ---------------- final: out(f32) = x2 + buf ----------------
__global__ __launch_bounds__(256) void final_add(const float* __restrict__ x2f,
                                                 const float* __restrict__ buf,
                                                 float* __restrict__ out) {
    long i = ((long)blockIdx.x * 256 + threadIdx.x) * 4;
    float4 a = *(const float4*)(x2f + i);
    float4 b = *(const float4*)(buf + i);
    float4 o = {a.x + b.x, a.y + b.y, a.z + b.z, a.w + b.w};
    *(float4*)(out + i) = o;
}

extern "C" void kernel_launch(void* const* d_in, const int* in_sizes, int n_in,
                              void* d_out, int out_size, void* d_ws, size_t ws_size,
                              hipStream_t stream) {
    const float* x     = (const float*)d_in[0];
    const float* noise = (const float*)d_in[1];
    const float* wq = (const float*)d_in[2];
    const float* bq = (const float*)d_in[3];
    const float* wk = (const float*)d_in[4];
    const float* bk = (const float*)d_in[5];
    const float* wv = (const float*)d_in[6];
    const float* bv = (const float*)d_in[7];
    const float* wo = (const float*)d_in[8];
    const float* bo = (const float*)d_in[9];
    const float* ln1_s = (const float*)d_in[10];
    const float* ln1_b = (const float*)d_in[11];
    const float* ln2_s = (const float*)d_in[12];
    const float* ln2_b = (const float*)d_in[13];
    const float* r_w = (const float*)d_in[14];
    const float* r_b = (const float*)d_in[15];
    const float* n_w = (const float*)d_in[16];
    const float* n_b = (const float*)d_in[17];
    const float* e_w1 = (const float*)d_in[18];
    const float* e_b1 = (const float*)d_in[19];
    const float* e_w2 = (const float*)d_in[20];
    const float* e_b2 = (const float*)d_in[21];

    char* ws = (char*)d_ws;
    // ---- overlaid workspace map (see comment at top) ----
    float* vf   = (float*)(ws + 0);                 // -> x2f
    float* x2f  = vf;
    float* h1f  = (float*)(ws + 12 * MB);
    float* schunk = (float*)(ws + 12 * MB);         // 24 MB (6 heads)
    unsigned short* eh = (unsigned short*)(ws + 12 * MB);  // 24 MB (8192 x 1536)
    float* of   = (float*)(ws + 36 * MB);           // -> buf
    float* buf  = of;
    float* qf   = (float*)(ws + 48 * MB);           // -> h2f
    float* h2f  = qf;
    unsigned short* khi  = (unsigned short*)(ws + 60 * MB);
    unsigned short* klo  = (unsigned short*)(ws + 66 * MB);
    unsigned short* vthi = (unsigned short*)(ws + 72 * MB);
    unsigned short* vtlo = (unsigned short*)(ws + 78 * MB);
    unsigned short* whalf = (unsigned short*)(ws + 60 * MB);  // 18 MB, MoE era
    unsigned short* wqTh = (unsigned short*)(ws + 84 * MB);
    unsigned short* wqTl = wqTh + (size_t)Dn * Dn;
    unsigned short* wkTh = wqTl + (size_t)Dn * Dn;
    unsigned short* wkTl = wkTh + (size_t)Dn * Dn;
    unsigned short* wvTh = wkTl + (size_t)Dn * Dn;
    unsigned short* wvTl = wvTh + (size_t)Dn * Dn;
    unsigned short* woTh = wvTl + (size_t)Dn * Dn;
    unsigned short* woTl = woTh + (size_t)Dn * Dn;
    char* misc = ws + 84 * MB + (size_t)8 * Dn * Dn * 2;
    float* gates = (float*)misc;                     // 2*Tn floats
    int* ind  = (int*)(misc + 2 * Tn * 4);           // 2*Tn ints
    int* meta = (int*)(misc + 4 * Tn * 4);           // 32 ints
    int* rows = (int*)(misc + 4 * Tn * 4 + 256);     // NROWS ints

    dim3 blk(256);
    // attention weight transposes ([D,D] f32 -> bf16 hi/lo [D,D]^T)
    transpose_f32<<<dim3(12, 12, 1), blk, 0, stream>>>(wq, Dn, 0, wqTh, wqTl, Dn, 0);
    transpose_f32<<<dim3(12, 12, 1), blk, 0, stream>>>(wk, Dn, 0, wkTh, wkTl, Dn, 0);
    transpose_f32<<<dim3(12, 12, 1), blk, 0, stream>>>(wv, Dn, 0, wvTh, wvTl, Dn, 0);
    transpose_f32<<<dim3(12, 12, 1), blk, 0, stream>>>(wo, Dn, 0, woTh, woTl, Dn, 0);
    // LN1
    ln_kernel<<<dim3(Tn), blk, 0, stream>>>(x, ln1_s, ln1_b, h1f);
    // QKV (split A x split W, fp32-grade)
    gemm_split<<<dim3(12, 32, 1), blk, 0, stream>>>(h1f, Dn, 0, wqTh, wqTl, Dn, 0, bq,
                                                    nullptr, qf, nullptr, nullptr, Dn, 0, Dn, 1, 0);
    gemm_split<<<dim3(12, 32, 1), blk, 0, stream>>>(h1f, Dn, 0, wkTh, wkTl, Dn, 0, bk,
                                                    nullptr, nullptr, khi, klo, Dn, 0, Dn, 1, 0);
    gemm_split<<<dim3(12, 32, 1), blk, 0, stream>>>(h1f, Dn, 0, wvTh, wvTl, Dn, 0, bv,
                                                    nullptr, vf, nullptr, nullptr, Dn, 0, Dn, 1, 0);
    vtrans<<<dim3(16, 1, 48), blk, 0, stream>>>(vf, vthi, vtlo);
    // zero PV accumulator
    hipMemsetAsync(of, 0, (size_t)Tn * Dn * 4, stream);
    // attention in chunks of 6 heads
    for (int b = 0; b < 4; ++b) {
        for (int hg = 0; hg < 2; ++hg) {
            long tb = (long)b * Sn * Dn;
            int hoff = hg * 6 * 64;
            gemm_split<<<dim3(16, 8, 6), blk, 0, stream>>>(
                qf + tb + hoff, Dn, 64,
                khi + tb + hoff, klo + tb + hoff, Dn, 64,
                nullptr, nullptr, schunk, nullptr, nullptr, 1024, (long)1024 * 1024, HDn, 1, 0);
            softmax_rows<<<dim3(6 * 1024), blk, 0, stream>>>(schunk);
            gemm_split<<<dim3(1, 8, 24), blk, 0, stream>>>(
                schunk, 1024, (long)1024 * 1024,
                vthi + (long)(b * 12 + hg * 6) * 64 * 1024,
                vtlo + (long)(b * 12 + hg * 6) * 64 * 1024, 1024, (long)64 * 1024,
                nullptr, nullptr, of + tb + hoff, nullptr, nullptr, Dn, 64, Sn, 4, 1);
        }
    }
    // output projection + residual -> x2
    gemm_split<<<dim3(12, 32, 1), blk, 0, stream>>>(of, Dn, 0, woTh, woTl, Dn, 0, bo,
                                                    x, x2f, nullptr, nullptr, Dn, 0, Dn, 1, 0);
    // LN2
    ln_kernel<<<dim3(Tn), blk, 0, stream>>>(x2f, ln2_s, ln2_b, h2f);
    // zero MoE accumulator (of is dead now; same region)
    hipMemsetAsync(buf, 0, (size_t)Tn * Dn * 4, stream);
    // routing
    zero16<<<1, 64, 0, stream>>>(meta);
    router_kernel<<<dim3(Tn), blk, 0, stream>>>(h2f, r_w, r_b, n_w, n_b, noise, gates, ind, meta);
    prefix_kernel<<<1, 1, 0, stream>>>(meta, meta + 16);
    build_rows<<<dim3(16), blk, 0, stream>>>(ind, meta + 16, meta + 8, rows);
    // sparse experts, two DFF halves through one 18 MB transposed-weight region
    for (int h = 0; h < 2; ++h) {
        // w1 half: src e_w1[e][d][dff-slice] (f32 [768 x 1536] slab, row stride 3072) -> bf16 [1536 x 768]
        transpose_f32<<<dim3(24, 12, 8), blk, 0, stream>>>(
            e_w1 + (size_t)h * DHALF, DFFn, (long)Dn * DFFn, whalf, nullptr, Dn, (long)DHALF * Dn);
        moe_gemm1<<<dim3(12, 32, 8), blk, 0, stream>>>(h2f, whalf, e_b1, rows, meta, eh, h);
        // w2 half: src e_w2[e][dff-slice][d] (f32 [1536 x 768] slab, row stride 768) -> bf16 [768 x 1536]
        transpose_f32<<<dim3(12, 24, 8), blk, 0, stream>>>(
            e_w2 + (size_t)h * DHALF * Dn, Dn, (long)DFFn * Dn, whalf, nullptr, DHALF, (long)Dn * DHALF);
        moe_gemm2<<<dim3(6, 32, 8), blk, 0, stream>>>(eh, whalf, h == 0 ? e_b2 : nullptr,
                                                      rows, meta, gates, buf);
    }
    // final residual add
    final_add<<<dim3(Tn * Dn / 1024), blk, 0, stream>>>(x2f, buf, (float*)d_out);
}

// Round 4
// 1176.284 us; speedup vs baseline: 1.1335x; 1.1335x over previous
//
#include <hip/hip_runtime.h>

#define DEV static __device__ __forceinline__

typedef __attribute__((ext_vector_type(8))) short v8s;
typedef __attribute__((ext_vector_type(4))) float v4f;

constexpr int Bn = 4, Sn = 1024, Dn = 768, NHn = 12, HDn = 64, En = 8, DFFn = 3072;
constexpr int Tn = Bn * Sn;          // 4096 tokens
constexpr int NROWS = 2 * Tn;        // 8192 gathered expert rows
constexpr int DHALF = DFFn / 2;      // 1536 (MoE processed in two DFF halves)
constexpr size_t MB = 1024 * 1024;

// ---- workspace map (~93.2 MB; lifetime-overlaid regions) ----
// [0,12)    vf (V out, f32)            -> x2f (attn residual out, lives to end)
// [12,36)   h1f (12, LN1 out) -> schunk (24, 6-head scores) -> eh (24, bf16 8192x1536)
// [36,48)   of (f32 PV accum, atomic)  -> buf (f32 MoE accum, atomic)
// [48,60)   qf (Q out f32)             -> h2f (LN2 out f32, lives through MoE)
// [60,78)   khi(6)+klo(6)+vthi(6)      -> whalf (18, per-half transposed expert weights)
// [78,84)   vtlo(6)                    -> (dead in MoE era)
// [84,93)   wqkvTh(3.375) wqkvTl(3.375) woTh(1.125) woTl(1.125)
// [93,93.2) bqkv, rwt, gates, ind, meta, rows

DEV float bf2f(unsigned short h) {
    union { unsigned int u; float f; } c; c.u = ((unsigned int)h) << 16; return c.f;
}
DEV unsigned short f2bf(float f) {   // round-to-nearest-even
    union { float f; unsigned int u; } c; c.f = f;
    return (unsigned short)((c.u + 0x7fffu + ((c.u >> 16) & 1u)) >> 16);
}
DEV v4f mfma16(v8s a, v8s b, v4f c) {
    return __builtin_amdgcn_mfma_f32_16x16x32_bf16(a, b, c, 0, 0, 0);
}

// ---------------- transpose fp32 src -> bf16 hi (+ optional lo) ----------------
__global__ __launch_bounds__(256) void transpose_f32(const float* __restrict__ src,
                                                     int src_ld, long src_zs,
                                                     unsigned short* __restrict__ dsthi,
                                                     unsigned short* __restrict__ dstlo,
                                                     int dst_ld, long dst_zs) {
    src += (long)blockIdx.z * src_zs;
    dsthi += (long)blockIdx.z * dst_zs;
    if (dstlo) dstlo += (long)blockIdx.z * dst_zs;
    __shared__ float tile[64][65];
    int tid = threadIdx.x, tx = blockIdx.x, ty = blockIdx.y;
    int r = tid >> 2, c0 = (tid & 3) * 16;
    const float* sp = src + (long)(ty * 64 + r) * src_ld + tx * 64 + c0;
#pragma unroll
    for (int i = 0; i < 4; ++i) {
        float4 f = *(const float4*)(sp + i * 4);
        tile[r][c0 + i * 4 + 0] = f.x;
        tile[r][c0 + i * 4 + 1] = f.y;
        tile[r][c0 + i * 4 + 2] = f.z;
        tile[r][c0 + i * 4 + 3] = f.w;
    }
    __syncthreads();
    int dl = tid >> 2, s0 = (tid & 3) * 16;
    unsigned short hh[16] __attribute__((aligned(16)));
    unsigned short ll[16] __attribute__((aligned(16)));
#pragma unroll
    for (int i = 0; i < 16; ++i) {
        float f = tile[s0 + i][dl];
        unsigned short h0 = f2bf(f);
        hh[i] = h0;
        ll[i] = f2bf(f - bf2f(h0));
    }
    long o = (long)(tx * 64 + dl) * dst_ld + ty * 64 + s0;
    *(uint4*)(dsthi + o) = ((uint4*)hh)[0];
    *(uint4*)(dsthi + o + 8) = ((uint4*)hh)[1];
    if (dstlo) {
        *(uint4*)(dstlo + o) = ((uint4*)ll)[0];
        *(uint4*)(dstlo + o + 8) = ((uint4*)ll)[1];
    }
}

// ---------------- LayerNorm (f32 in, f32 out) ----------------
__global__ __launch_bounds__(256) void ln_kernel(const float* __restrict__ in_f,
                                                 const float* __restrict__ sc,
                                                 const float* __restrict__ bi,
                                                 float* __restrict__ outf) {
    int row = blockIdx.x, tid = threadIdx.x;
    long base = (long)row * Dn;
    float x[3];
#pragma unroll
    for (int j = 0; j < 3; ++j) x[j] = in_f[base + tid + j * 256];
    __shared__ float red[4];
    float s = x[0] + x[1] + x[2];
    for (int off = 32; off; off >>= 1) s += __shfl_down(s, off, 64);
    if ((tid & 63) == 0) red[tid >> 6] = s;
    __syncthreads();
    float mean = (red[0] + red[1] + red[2] + red[3]) * (1.0f / Dn);
    __syncthreads();
    float ss = 0.f;
#pragma unroll
    for (int j = 0; j < 3; ++j) { float d0 = x[j] - mean; ss += d0 * d0; }
    for (int off = 32; off; off >>= 1) ss += __shfl_down(ss, off, 64);
    if ((tid & 63) == 0) red[tid >> 6] = ss;
    __syncthreads();
    float var = (red[0] + red[1] + red[2] + red[3]) * (1.0f / Dn);
    float rstd = 1.0f / sqrtf(var + 1e-5f);
#pragma unroll
    for (int j = 0; j < 3; ++j) {
        int d = tid + j * 256;
        outf[base + d] = (x[j] - mean) * rstd * sc[d] + bi[d];
    }
}

// ---------------- LN2 fused with router (no atomics) ----------------
// rwt: [16][768] packed (r_w rows 0..8, n_w rows 8..16)
__global__ __launch_bounds__(256) void ln2_router(const float* __restrict__ in_f,
                                                  const float* __restrict__ sc,
                                                  const float* __restrict__ bi,
                                                  const float* __restrict__ rwt,
                                                  const float* __restrict__ rb,
                                                  const float* __restrict__ nb,
                                                  const float* __restrict__ noise,
                                                  float* __restrict__ h2f,
                                                  float* __restrict__ gates,
                                                  int* __restrict__ ind) {
    int t = blockIdx.x, tid = threadIdx.x;
    int w = tid >> 6, lane = tid & 63;
    long base = (long)t * Dn;
    float x[3];
#pragma unroll
    for (int j = 0; j < 3; ++j) x[j] = in_f[base + tid + j * 256];
    __shared__ float red[4];
    float s = x[0] + x[1] + x[2];
    for (int off = 32; off; off >>= 1) s += __shfl_down(s, off, 64);
    if ((tid & 63) == 0) red[tid >> 6] = s;
    __syncthreads();
    float mean = (red[0] + red[1] + red[2] + red[3]) * (1.0f / Dn);
    __syncthreads();
    float ss = 0.f;
#pragma unroll
    for (int j = 0; j < 3; ++j) { float d0 = x[j] - mean; ss += d0 * d0; }
    for (int off = 32; off; off >>= 1) ss += __shfl_down(ss, off, 64);
    if ((tid & 63) == 0) red[tid >> 6] = ss;
    __syncthreads();
    float var = (red[0] + red[1] + red[2] + red[3]) * (1.0f / Dn);
    float rstd = 1.0f / sqrtf(var + 1e-5f);
    float y[3];
#pragma unroll
    for (int j = 0; j < 3; ++j) {
        int d = tid + j * 256;
        y[j] = (x[j] - mean) * rstd * sc[d] + bi[d];
        h2f[base + d] = y[j];
    }
    // router logits: 16 dot products, coalesced rwt reads
    float acc[16];
#pragma unroll
    for (int e = 0; e < 16; ++e) {
        const float* wp = rwt + e * Dn + tid;
        acc[e] = y[0] * wp[0] + y[1] * wp[256] + y[2] * wp[512];
    }
#pragma unroll
    for (int e = 0; e < 16; ++e)
        for (int off = 32; off; off >>= 1) acc[e] += __shfl_down(acc[e], off, 64);
    __shared__ float red2[4][16];
    if (lane == 0)
#pragma unroll
        for (int e = 0; e < 16; ++e) red2[w][e] = acc[e];
    __syncthreads();
    if (tid == 0) {
        float noisy[8];
#pragma unroll
        for (int e = 0; e < 8; ++e) {
            float lg = red2[0][e] + red2[1][e] + red2[2][e] + red2[3][e] + rb[e];
            float nv = red2[0][8 + e] + red2[1][8 + e] + red2[2][8 + e] + red2[3][8 + e] + nb[e];
            float sp = fmaxf(nv, 0.f) + log1pf(expf(-fabsf(nv)));
            noisy[e] = lg + noise[(long)t * En + e] * sp;
        }
        int i0 = 0;
        for (int e = 1; e < 8; ++e) if (noisy[e] > noisy[i0]) i0 = e;
        int i1 = (i0 == 0) ? 1 : 0;
        for (int e = 0; e < 8; ++e) if (e != i0 && noisy[e] > noisy[i1]) i1 = e;
        float mm = fmaxf(noisy[i0], noisy[i1]);
        float e0 = expf(noisy[i0] - mm), e1 = expf(noisy[i1] - mm);
        float inv = 1.0f / (e0 + e1);
        gates[t] = e0 * inv;
        gates[Tn + t] = e1 * inv;
        ind[t] = i0;
        ind[Tn + t] = i1;
    }
}

// ---------------- deterministic counting sort of 8192 (tok,slot) entries ----------------
// single block, 1024 threads, zero global atomics
__global__ __launch_bounds__(1024) void sort_rows(const int* __restrict__ ind,
                                                  int* __restrict__ meta,
                                                  int* __restrict__ rows) {
    __shared__ int hist[1024][8];
    __shared__ int bb[9];
    __shared__ int tot[8];
    int tid = threadIdx.x;
    int codes[8];
    int h[8] = {0, 0, 0, 0, 0, 0, 0, 0};
#pragma unroll
    for (int k = 0; k < 8; ++k) {
        int i = tid * 8 + k;
        int e = ind[(i & 1) * Tn + (i >> 1)];
        codes[k] = e;
        ++h[e];
    }
#pragma unroll
    for (int e = 0; e < 8; ++e) hist[tid][e] = h[e];
    __syncthreads();
    if (tid < 8) {
        int run = 0;
        for (int tt = 0; tt < 1024; ++tt) {
            int v = hist[tt][tid];
            hist[tt][tid] = run;
            run += v;
        }
        tot[tid] = run;
        meta[tid] = run;            // counts
    }
    __syncthreads();
    if (tid == 0) {
        int b = 0;
        for (int e = 0; e < 8; ++e) {
            bb[e] = b;
            meta[16 + e] = b;
            b += tot[e];
        }
        bb[8] = b;
        meta[24] = b;
    }
    __syncthreads();
    int c[8];
#pragma unroll
    for (int e = 0; e < 8; ++e) c[e] = hist[tid][e];
#pragma unroll
    for (int k = 0; k < 8; ++k) {
        int e = codes[k];
        rows[bb[e] + c[e]] = tid * 8 + k;   // value == t*2+slot
        ++c[e];
    }
}

// ---------------- tiny packers ----------------
__global__ void pack_router(const float* __restrict__ rw, const float* __restrict__ nw,
                            float* __restrict__ rwt) {
    int idx = blockIdx.x * 256 + threadIdx.x;   // [0, 16*768)
    int e = idx / Dn, d = idx - e * Dn;
    rwt[idx] = (e < 8) ? rw[d * En + e] : nw[d * En + (e - 8)];
}

__global__ void pack_bias(const float* __restrict__ bq, const float* __restrict__ bk,
                          const float* __restrict__ bv, float* __restrict__ bqkv) {
    int i = blockIdx.x * 256 + threadIdx.x;     // [0, 2304)
    bqkv[i] = (i < 768) ? bq[i] : (i < 1536 ? bk[i - 768] : bv[i - 1536]);
}

// ---------------- split-bf16 fp32-grade GEMM ----------------
// C = A(f32, split hi/lo in staging) @ B^T (+bias)(+resid)
// qkvmode: cols [0,768)->Cf(f32), [768,1536)->Chi/Clo(bf16 split), [1536,2304)->Cf2(f32)
__global__ __launch_bounds__(256) void gemm_split(const float* __restrict__ A, int lda, long za,
                                                  const unsigned short* __restrict__ Bhi,
                                                  const unsigned short* __restrict__ Blo, int ldb, long zb,
                                                  const float* __restrict__ bias,
                                                  const float* __restrict__ resid,
                                                  float* __restrict__ Cf,
                                                  unsigned short* __restrict__ Chi,
                                                  unsigned short* __restrict__ Clo,
                                                  int ldc, long zc, int K, int zdiv, int catomic,
                                                  float* __restrict__ Cf2, int qkvmode) {
    int z = blockIdx.z;
    int zi = z / zdiv, ks = z - zi * zdiv;
    int Klen = K / zdiv, k0base = ks * Klen;
    A += (long)zi * za;
    Bhi += (long)zi * zb;
    if (Blo) Blo += (long)zi * zb;
    long coff = (long)zi * zc;
    int n0 = blockIdx.x * 64, m0 = blockIdx.y * 128;
    int tid = threadIdx.x, w = tid >> 6, lane = tid & 63, quad = lane >> 4, l16 = lane & 15;
    __shared__ unsigned short Ah[128][40], Al[128][40], Bh[64][40], Bl[64][40];
    v4f acc[2][4] = {};
    int ar = tid >> 1, ac = (tid & 1) * 16;
    int br = tid >> 2, bc = (tid & 3) * 8;
    const bool hasblo = (Blo != nullptr);
    int nsteps = Klen >> 5;
    for (int kt = 0; kt < nsteps; ++kt) {
        int k0 = k0base + (kt << 5);
        const float* ap = A + (long)(m0 + ar) * lda + (k0 + ac);
        float4 f0 = *(const float4*)(ap);
        float4 f1 = *(const float4*)(ap + 4);
        float4 f2 = *(const float4*)(ap + 8);
        float4 f3 = *(const float4*)(ap + 12);
        float fv[16] = {f0.x, f0.y, f0.z, f0.w, f1.x, f1.y, f1.z, f1.w,
                        f2.x, f2.y, f2.z, f2.w, f3.x, f3.y, f3.z, f3.w};
        unsigned short hh[16] __attribute__((aligned(16)));
        unsigned short ll[16] __attribute__((aligned(16)));
#pragma unroll
        for (int i = 0; i < 16; ++i) {
            unsigned short h = f2bf(fv[i]);
            hh[i] = h;
            ll[i] = f2bf(fv[i] - bf2f(h));
        }
        *(uint4*)&Ah[ar][ac] = ((uint4*)hh)[0];
        *(uint4*)&Ah[ar][ac + 8] = ((uint4*)hh)[1];
        *(uint4*)&Al[ar][ac] = ((uint4*)ll)[0];
        *(uint4*)&Al[ar][ac + 8] = ((uint4*)ll)[1];
        const unsigned short* bp = Bhi + (long)(n0 + br) * ldb + (k0 + bc);
        *(uint4*)&Bh[br][bc] = *(const uint4*)bp;
        if (hasblo)
            *(uint4*)&Bl[br][bc] = *(const uint4*)(Blo + (long)(n0 + br) * ldb + (k0 + bc));
        __syncthreads();
        v8s ah0 = *(const v8s*)&Ah[w * 32 + l16][quad * 8];
        v8s ah1 = *(const v8s*)&Ah[w * 32 + 16 + l16][quad * 8];
        v8s al0 = *(const v8s*)&Al[w * 32 + l16][quad * 8];
        v8s al1 = *(const v8s*)&Al[w * 32 + 16 + l16][quad * 8];
#pragma unroll
        for (int nt = 0; nt < 4; ++nt) {
            v8s bh = *(const v8s*)&Bh[nt * 16 + l16][quad * 8];
            acc[0][nt] = mfma16(ah0, bh, acc[0][nt]);
            acc[1][nt] = mfma16(ah1, bh, acc[1][nt]);
            acc[0][nt] = mfma16(al0, bh, acc[0][nt]);
            acc[1][nt] = mfma16(al1, bh, acc[1][nt]);
            if (hasblo) {
                v8s bl = *(const v8s*)&Bl[nt * 16 + l16][quad * 8];
                acc[0][nt] = mfma16(ah0, bl, acc[0][nt]);
                acc[1][nt] = mfma16(ah1, bl, acc[1][nt]);
                acc[0][nt] = mfma16(al0, bl, acc[0][nt]);
                acc[1][nt] = mfma16(al1, bl, acc[1][nt]);
            }
        }
        __syncthreads();
    }
#pragma unroll
    for (int mt = 0; mt < 2; ++mt)
#pragma unroll
        for (int nt = 0; nt < 4; ++nt)
#pragma unroll
            for (int r = 0; r < 4; ++r) {
                int row = m0 + w * 32 + mt * 16 + quad * 4 + r;
                int col = n0 + nt * 16 + l16;
                float v = acc[mt][nt][r];
                if (bias) v += bias[col];
                if (qkvmode) {
                    int seg = (col >= 1536) ? 2 : (col >= 768 ? 1 : 0);
                    int c = col - seg * 768;
                    long ci = (long)row * 768 + c;
                    if (seg == 0) Cf[ci] = v;
                    else if (seg == 1) {
                        unsigned short h = f2bf(v);
                        Chi[ci] = h;
                        Clo[ci] = f2bf(v - bf2f(h));
                    } else Cf2[ci] = v;
                    continue;
                }
                long ci = coff + (long)row * ldc + col;
                if (resid) v += resid[ci];
                if (catomic) {
                    atomicAdd(&Cf[ci], v);
                } else {
                    if (Cf) Cf[ci] = v;
                    if (Chi) {
                        unsigned short h = f2bf(v);
                        Chi[ci] = h;
                        if (Clo) Clo[ci] = f2bf(v - bf2f(h));
                    }
                }
            }
}

// ---------------- V transpose+split: v[b,s,h,d] f32 -> vt[g=b*12+h][d][s] bf16 hi/lo ----------
__global__ __launch_bounds__(256) void vtrans(const float* __restrict__ vf,
                                              unsigned short* __restrict__ vthi,
                                              unsigned short* __restrict__ vtlo) {
    int g = blockIdx.z, b = g / NHn, h = g % NHn;
    int stile = blockIdx.x, tid = threadIdx.x;
    __shared__ float tile[64][65];
    int sl = tid >> 2, c0 = (tid & 3) * 16;
    const float* vp = vf + (long)(b * Sn + stile * 64 + sl) * Dn + h * 64 + c0;
#pragma unroll
    for (int i = 0; i < 4; ++i) {
        float4 f = *(const float4*)(vp + i * 4);
        tile[sl][c0 + i * 4 + 0] = f.x;
        tile[sl][c0 + i * 4 + 1] = f.y;
        tile[sl][c0 + i * 4 + 2] = f.z;
        tile[sl][c0 + i * 4 + 3] = f.w;
    }
    __syncthreads();
    int dl = tid >> 2, s0 = (tid & 3) * 16;
    unsigned short hh[16] __attribute__((aligned(16)));
    unsigned short ll[16] __attribute__((aligned(16)));
#pragma unroll
    for (int i = 0; i < 16; ++i) {
        float f = tile[s0 + i][dl];
        unsigned short h0 = f2bf(f);
        hh[i] = h0;
        ll[i] = f2bf(f - bf2f(h0));
    }
    long o = (long)(g * 64 + dl) * Sn + stile * 64 + s0;
    *(uint4*)(vthi + o) = ((uint4*)hh)[0];
    *(uint4*)(vthi + o + 8) = ((uint4*)hh)[1];
    *(uint4*)(vtlo + o) = ((uint4*)ll)[0];
    *(uint4*)(vtlo + o + 8) = ((uint4*)ll)[1];
}

// ---------------- softmax over rows of 1024 (scale 1/8 applied) ----------------
__global__ __launch_bounds__(256) void softmax_rows(float* __restrict__ S) {
    long base = (long)blockIdx.x * 1024;
    int tid = threadIdx.x;
    float4 v = *(float4*)(S + base + tid * 4);
    v.x *= 0.125f; v.y *= 0.125f; v.z *= 0.125f; v.w *= 0.125f;
    __shared__ float redm[4], reds[4];
    float m = fmaxf(fmaxf(v.x, v.y), fmaxf(v.z, v.w));
    for (int off = 32; off; off >>= 1) m = fmaxf(m, __shfl_down(m, off, 64));
    if ((tid & 63) == 0) redm[tid >> 6] = m;
    __syncthreads();
    float M = fmaxf(fmaxf(redm[0], redm[1]), fmaxf(redm[2], redm[3]));
    float e0 = expf(v.x - M), e1 = expf(v.y - M), e2 = expf(v.z - M), e3 = expf(v.w - M);
    float s = e0 + e1 + e2 + e3;
    for (int off = 32; off; off >>= 1) s += __shfl_down(s, off, 64);
    if ((tid & 63) == 0) reds[tid >> 6] = s;
    __syncthreads();
    float inv = 1.0f / (reds[0] + reds[1] + reds[2] + reds[3]);
    float4 o = {e0 * inv, e1 * inv, e2 * inv, e3 * inv};
    *(float4*)(S + base + tid * 4) = o;
}

// ---------------- MoE stage 1 (per DFF half): eh = relu(h2 @ W1t[e]^T + b1) ----------------
__global__ __launch_bounds__(256) void moe_gemm1(const float* __restrict__ h2f,
                                                 const unsigned short* __restrict__ W1t,
                                                 const float* __restrict__ eb1,
                                                 const int* __restrict__ rows,
                                                 const int* __restrict__ meta,
                                                 unsigned short* __restrict__ eh,
                                                 int half) {
    int e = blockIdx.z;
    int cnt = meta[e];
    int mb = blockIdx.y * 128;
    if (mb >= cnt) return;
    int base_e = meta[16 + e];
    int valid = cnt - mb; if (valid > 128) valid = 128;
    int tid = threadIdx.x;
    __shared__ int toks[128];
    if (tid < 128) {
        int idx = mb + tid;
        toks[tid] = rows[base_e + (idx < cnt ? idx : 0)];
    }
    __shared__ unsigned short As[128][40], Bs[128][40];
    int w = tid >> 6, lane = tid & 63, quad = lane >> 4, l16 = lane & 15;
    int wm = w >> 1, wn = w & 1;
    v4f acc[4][4] = {};
    int ar = tid >> 1, ac = (tid & 1) * 16;
    int nb0 = blockIdx.x * 128;
    const unsigned short* Wb = W1t + (long)e * DHALF * Dn;
    __syncthreads();
    for (int kt = 0; kt < Dn / 32; ++kt) {
        int k0 = kt * 32;
        int tok = toks[ar] >> 1;
        const float* apg = h2f + (long)tok * Dn + k0 + ac;
        float4 f0 = ((const float4*)apg)[0];
        float4 f1 = ((const float4*)apg)[1];
        float4 f2 = ((const float4*)apg)[2];
        float4 f3 = ((const float4*)apg)[3];
        float fv[16] = {f0.x, f0.y, f0.z, f0.w, f1.x, f1.y, f1.z, f1.w,
                        f2.x, f2.y, f2.z, f2.w, f3.x, f3.y, f3.z, f3.w};
        unsigned short hh[16] __attribute__((aligned(16)));
#pragma unroll
        for (int i = 0; i < 16; ++i) hh[i] = f2bf(fv[i]);
        *(uint4*)&As[ar][ac] = ((uint4*)hh)[0];
        *(uint4*)&As[ar][ac + 8] = ((uint4*)hh)[1];
        const unsigned short* bpg = Wb + (long)(nb0 + ar) * Dn + k0 + ac;
        *(uint4*)&Bs[ar][ac] = ((const uint4*)bpg)[0];
        *(uint4*)&Bs[ar][ac + 8] = ((const uint4*)bpg)[1];
        __syncthreads();
        v8s af[4];
#pragma unroll
        for (int mt = 0; mt < 4; ++mt) af[mt] = *(const v8s*)&As[wm * 64 + mt * 16 + l16][quad * 8];
#pragma unroll
        for (int nt = 0; nt < 4; ++nt) {
            v8s bb = *(const v8s*)&Bs[wn * 64 + nt * 16 + l16][quad * 8];
#pragma unroll
            for (int mt = 0; mt < 4; ++mt) acc[mt][nt] = mfma16(af[mt], bb, acc[mt][nt]);
        }
        __syncthreads();
    }
#pragma unroll
    for (int mt = 0; mt < 4; ++mt)
#pragma unroll
        for (int nt = 0; nt < 4; ++nt)
#pragma unroll
            for (int r = 0; r < 4; ++r) {
                int rl = wm * 64 + mt * 16 + quad * 4 + r;
                if (rl < valid) {
                    int col = nb0 + wn * 64 + nt * 16 + l16;
                    float v = acc[mt][nt][r] + eb1[e * DFFn + half * DHALF + col];
                    v = fmaxf(v, 0.f);
                    eh[(long)(base_e + mb + rl) * DHALF + col] = f2bf(v);
                }
            }
}

// ---------------- MoE stage 2 (per DFF half): buf[tok] += gate*(eh @ W2t[e]^T (+b2)) --------
__global__ __launch_bounds__(256) void moe_gemm2(const unsigned short* __restrict__ eh,
                                                 const unsigned short* __restrict__ W2t,
                                                 const float* __restrict__ eb2,
                                                 const int* __restrict__ rows,
                                                 const int* __restrict__ meta,
                                                 const float* __restrict__ gates,
                                                 float* __restrict__ buf) {
    int e = blockIdx.z;
    int cnt = meta[e];
    int mb = blockIdx.y * 128;
    if (mb >= cnt) return;
    int base_e = meta[16 + e];
    int valid = cnt - mb; if (valid > 128) valid = 128;
    int tid = threadIdx.x;
    __shared__ int toks[128];
    if (tid < 128) {
        int idx = mb + tid;
        toks[tid] = rows[base_e + (idx < cnt ? idx : 0)];
    }
    __shared__ unsigned short As[128][40], Bs[128][40];
    int w = tid >> 6, lane = tid & 63, quad = lane >> 4, l16 = lane & 15;
    int wm = w >> 1, wn = w & 1;
    v4f acc[4][4] = {};
    int ar = tid >> 1, ac = (tid & 1) * 16;
    int nb0 = blockIdx.x * 128;
    const unsigned short* Wb = W2t + (long)e * Dn * DHALF;
    __syncthreads();
    for (int kt = 0; kt < DHALF / 32; ++kt) {
        int k0 = kt * 32;
        long arow = (long)base_e + mb + ar;
        if (arow > NROWS - 1) arow = NROWS - 1;
        const unsigned short* apg = eh + arow * DHALF + k0 + ac;
        *(uint4*)&As[ar][ac] = ((const uint4*)apg)[0];
        *(uint4*)&As[ar][ac + 8] = ((const uint4*)apg)[1];
        const unsigned short* bpg = Wb + (long)(nb0 + ar) * DHALF + k0 + ac;
        *(uint4*)&Bs[ar][ac] = ((const uint4*)bpg)[0];
        *(uint4*)&Bs[ar][ac + 8] = ((const uint4*)bpg)[1];
        __syncthreads();
        v8s af[4];
#pragma unroll
        for (int mt = 0; mt < 4; ++mt) af[mt] = *(const v8s*)&As[wm * 64 + mt * 16 + l16][quad * 8];
#pragma unroll
        for (int nt = 0; nt < 4; ++nt) {
            v8s bb = *(const v8s*)&Bs[wn * 64 + nt * 16 + l16][quad * 8];
#pragma unroll
            for (int mt = 0; mt < 4; ++mt) acc[mt][nt] = mfma16(af[mt], bb, acc[mt][nt]);
        }
        __syncthreads();
    }
#pragma unroll
    for (int mt = 0; mt < 4; ++mt)
#pragma unroll
        for (int nt = 0; nt < 4; ++nt)
#pragma unroll
            for (int r = 0; r < 4; ++r) {
                int rl = wm * 64 + mt * 16 + quad * 4 + r;
                if (rl < valid) {
                    int col = nb0 + wn * 64 + nt * 16 + l16;
                    int code = toks[rl];
                    int tok = code >> 1, slot = code & 1;
                    float g = gates[slot * Tn + tok];
                    float v = acc[mt][nt][r];
                    if (eb2) v += eb2[e * Dn + col];
                    atomicAdd(&buf[(long)tok * Dn + col], v * g);
                }
            }
}

// ---------------- final: out(f32) = x2 + buf ----------------
__global__ __launch_bounds__(256) void final_add(const float* __restrict__ x2f,
                                                 const float* __restrict__ buf,
                                                 float* __restrict__ out) {
    long i = ((long)blockIdx.x * 256 + threadIdx.x) * 4;
    float4 a = *(const float4*)(x2f + i);
    float4 b = *(const float4*)(buf + i);
    float4 o = {a.x + b.x, a.y + b.y, a.z + b.z, a.w + b.w};
    *(float4*)(out + i) = o;
}

extern "C" void kernel_launch(void* const* d_in, const int* in_sizes, int n_in,
                              void* d_out, int out_size, void* d_ws, size_t ws_size,
                              hipStream_t stream) {
    const float* x     = (const float*)d_in[0];
    const float* noise = (const float*)d_in[1];
    const float* wq = (const float*)d_in[2];
    const float* bq = (const float*)d_in[3];
    const float* wk = (const float*)d_in[4];
    const float* bk = (const float*)d_in[5];
    const float* wv = (const float*)d_in[6];
    const float* bv = (const float*)d_in[7];
    const float* wo = (const float*)d_in[8];
    const float* bo = (const float*)d_in[9];
    const float* ln1_s = (const float*)d_in[10];
    const float* ln1_b = (const float*)d_in[11];
    const float* ln2_s = (const float*)d_in[12];
    const float* ln2_b = (const float*)d_in[13];
    const float* r_w = (const float*)d_in[14];
    const float* r_b = (const float*)d_in[15];
    const float* n_w = (const float*)d_in[16];
    const float* n_b = (const float*)d_in[17];
    const float* e_w1 = (const float*)d_in[18];
    const float* e_b1 = (const float*)d_in[19];
    const float* e_w2 = (const float*)d_in[20];
    const float* e_b2 = (const float*)d_in[21];

    char* ws = (char*)d_ws;
    float* vf   = (float*)(ws + 0);                 // -> x2f
    float* x2f  = vf;
    float* h1f  = (float*)(ws + 12 * MB);
    float* schunk = (float*)(ws + 12 * MB);         // 24 MB (6 heads)
    unsigned short* eh = (unsigned short*)(ws + 12 * MB);  // 24 MB (8192 x 1536)
    float* of   = (float*)(ws + 36 * MB);           // -> buf
    float* buf  = of;
    float* qf   = (float*)(ws + 48 * MB);           // -> h2f
    float* h2f  = qf;
    unsigned short* khi  = (unsigned short*)(ws + 60 * MB);
    unsigned short* klo  = (unsigned short*)(ws + 66 * MB);
    unsigned short* vthi = (unsigned short*)(ws + 72 * MB);
    unsigned short* vtlo = (unsigned short*)(ws + 78 * MB);
    unsigned short* whalf = (unsigned short*)(ws + 60 * MB);  // 18 MB, MoE era
    unsigned short* wqkvTh = (unsigned short*)(ws + 84 * MB);          // [2304][768]
    unsigned short* wqkvTl = wqkvTh + (size_t)3 * Dn * Dn;
    unsigned short* woTh = wqkvTl + (size_t)3 * Dn * Dn;
    unsigned short* woTl = woTh + (size_t)Dn * Dn;
    char* misc = (char*)(woTl + (size_t)Dn * Dn);
    float* bqkv = (float*)misc;                          // 2304 f
    float* rwt  = (float*)(misc + 2304 * 4);             // 16*768 f
    float* gates = (float*)(misc + 2304 * 4 + 12288 * 4);
    int* ind  = (int*)((char*)gates + 2 * Tn * 4);
    int* meta = (int*)((char*)ind + 2 * Tn * 4);
    int* rows = (int*)((char*)meta + 256);

    dim3 blk(256);
    // packed QKV weight transpose ([D,D] f32 -> bf16 hi/lo rows of [2304][768])
    transpose_f32<<<dim3(12, 12, 1), blk, 0, stream>>>(wq, Dn, 0, wqkvTh, wqkvTl, Dn, 0);
    transpose_f32<<<dim3(12, 12, 1), blk, 0, stream>>>(wk, Dn, 0,
        wqkvTh + (size_t)Dn * Dn, wqkvTl + (size_t)Dn * Dn, Dn, 0);
    transpose_f32<<<dim3(12, 12, 1), blk, 0, stream>>>(wv, Dn, 0,
        wqkvTh + (size_t)2 * Dn * Dn, wqkvTl + (size_t)2 * Dn * Dn, Dn, 0);
    transpose_f32<<<dim3(12, 12, 1), blk, 0, stream>>>(wo, Dn, 0, woTh, woTl, Dn, 0);
    pack_bias<<<dim3(9), blk, 0, stream>>>(bq, bk, bv, bqkv);
    pack_router<<<dim3(48), blk, 0, stream>>>(r_w, n_w, rwt);
    // LN1
    ln_kernel<<<dim3(Tn), blk, 0, stream>>>(x, ln1_s, ln1_b, h1f);
    // fused QKV (split A x split W, fp32-grade), 3-way epilogue
    gemm_split<<<dim3(36, 32, 1), blk, 0, stream>>>(h1f, Dn, 0, wqkvTh, wqkvTl, Dn, 0, bqkv,
                                                    nullptr, qf, khi, klo, Dn, 0, Dn, 1, 0, vf, 1);
    vtrans<<<dim3(16, 1, 48), blk, 0, stream>>>(vf, vthi, vtlo);
    hipMemsetAsync(of, 0, (size_t)Tn * Dn * 4, stream);
    // attention in chunks of 6 heads
    for (int b = 0; b < 4; ++b) {
        for (int hg = 0; hg < 2; ++hg) {
            long tb = (long)b * Sn * Dn;
            int hoff = hg * 6 * 64;
            gemm_split<<<dim3(16, 8, 6), blk, 0, stream>>>(
                qf + tb + hoff, Dn, 64,
                khi + tb + hoff, klo + tb + hoff, Dn, 64,
                nullptr, nullptr, schunk, nullptr, nullptr, 1024, (long)1024 * 1024,
                HDn, 1, 0, nullptr, 0);
            softmax_rows<<<dim3(6 * 1024), blk, 0, stream>>>(schunk);
            gemm_split<<<dim3(1, 8, 48), blk, 0, stream>>>(
                schunk, 1024, (long)1024 * 1024,
                vthi + (long)(b * 12 + hg * 6) * 64 * 1024,
                vtlo + (long)(b * 12 + hg * 6) * 64 * 1024, 1024, (long)64 * 1024,
                nullptr, nullptr, of + tb + hoff, nullptr, nullptr, Dn, 64,
                Sn, 8, 1, nullptr, 0);
        }
    }
    // output projection + residual -> x2
    gemm_split<<<dim3(12, 32, 1), blk, 0, stream>>>(of, Dn, 0, woTh, woTl, Dn, 0, bo,
                                                    x, x2f, nullptr, nullptr, Dn, 0, Dn, 1, 0,
                                                    nullptr, 0);
    // LN2 + router fused (no atomics)
    ln2_router<<<dim3(Tn), blk, 0, stream>>>(x2f, ln2_s, ln2_b, rwt, r_b, n_b, noise,
                                             h2f, gates, ind);
    hipMemsetAsync(buf, 0, (size_t)Tn * Dn * 4, stream);
    // deterministic token sort (single block, no atomics)
    sort_rows<<<dim3(1), dim3(1024), 0, stream>>>(ind, meta, rows);
    // sparse experts, two DFF halves through one 18 MB transposed-weight region
    for (int h = 0; h < 2; ++h) {
        transpose_f32<<<dim3(24, 12, 8), blk, 0, stream>>>(
            e_w1 + (size_t)h * DHALF, DFFn, (long)Dn * DFFn, whalf, nullptr, Dn, (long)DHALF * Dn);
        moe_gemm1<<<dim3(12, 32, 8), blk, 0, stream>>>(h2f, whalf, e_b1, rows, meta, eh, h);
        transpose_f32<<<dim3(12, 24, 8), blk, 0, stream>>>(
            e_w2 + (size_t)h * DHALF * Dn, Dn, (long)DFFn * Dn, whalf, nullptr, DHALF, (long)Dn * DHALF);
        moe_gemm2<<<dim3(6, 32, 8), blk, 0, stream>>>(eh, whalf, h == 0 ? e_b2 : nullptr,
                                                      rows, meta, gates, buf);
    }
    final_add<<<dim3(Tn * Dn / 1024), blk, 0, stream>>>(x2f, buf, (float*)d_out);
}